// Round 6
// baseline (493.079 us; speedup 1.0000x reference)
//
#include <hip/hip_runtime.h>

typedef __attribute__((ext_vector_type(8))) short short8;
typedef __attribute__((ext_vector_type(4))) float f32x4;
typedef __attribute__((ext_vector_type(4))) unsigned int u32x4;
typedef unsigned short ushort_t;

#define BB 4
#define HW 3136
#define NX (4*256*3136)          // total x elements

// k1 LDS regions: w1 [64][512B] @0, x dbuf @32768/@36864, bias/scv
#define K1_XB0 32768
#define K1_XB1 36864
#define K1_BIAS 40960
#define K1_SCV 41216
#define K1_TOT 41472

// k2 LDS regions (4-row tile): h 224*128 @0, w2p @28672, bias @36864
// wgt bf16 [64][232] @0 (aliases h+w2p after phase B)
#define K2_W2P 28672
#define K2_B2S 36864
#define K2_TOT 37120

__device__ __forceinline__ unsigned int f2bf(float f) {
    unsigned int u = __float_as_uint(f);
    return (u + 0x7FFFu + ((u >> 16) & 1u)) >> 16;   // RNE to bf16 bits
}

// k1: h = relu(conv1+bn) via bf16 MFMA, BN fold fused into w1 staging.
// All 64 x values per thread loaded UPFRONT (full-K register prefetch) so the
// 8 K-steps never wait on HBM. h_g[b][px][64c] bf16. Block = 56-px tile, 4 waves.
__global__ __launch_bounds__(256) void k1_mfma(
        const float* __restrict__ x, const float* __restrict__ w1,
        const float* __restrict__ gamma, const float* __restrict__ beta,
        const float* __restrict__ mean, const float* __restrict__ var,
        ushort_t* __restrict__ h_g) {
    __shared__ __align__(16) char lds[K1_TOT];
    int blk = blockIdx.x;
    int tile = blk % 56, b = blk / 56;
    int px0 = tile * 56;
    int tid = threadIdx.x;
    int lane = tid & 63, w = tid >> 6;

    // BN params FIRST (oldest in vmem queue -> consuming them doesn't drain x loads)
    float gs = 0.f, bs = 0.f, ms = 0.f, vs = 0.f;
    if (tid < 64) { gs = gamma[tid]; bs = beta[tid]; ms = mean[tid]; vs = var[tid]; }

    // issue ALL x loads upfront: thread -> (px = tid&63, cg = tid>>6), 8 c x 8 steps
    int spx = tid & 63, scg = tid >> 6;
    int gpx = min(px0 + spx, HW - 1);              // clamp pad px (masked at epilogue)
    const float* xbase = x + (size_t)b * 256 * HW + gpx;
    float xr[8][8];
#pragma unroll
    for (int s = 0; s < 8; s++)
#pragma unroll
        for (int u = 0; u < 8; u++)
            xr[s][u] = xbase[(size_t)(s * 32 + scg * 8 + u) * HW];

    if (tid < 64) {
        float sc = gs * rsqrtf(vs + 1e-5f);
        ((float*)(lds + K1_SCV))[tid] = sc;
        ((float*)(lds + K1_BIAS))[tid] = bs - ms * sc;
    }
    __syncthreads();

    // stage w1 [64o][256c] -> bf16*scale, rows 512B, XOR-swizzled
#pragma unroll
    for (int ii = 0; ii < 8; ii++) {
        int i = tid + ii * 256;
        int row = i >> 5, col8 = i & 31;
        const float* src = w1 + row * 256 + col8 * 8;
        f32x4 a = *(const f32x4*)src;
        f32x4 c = *(const f32x4*)(src + 4);
        float sc = ((const float*)(lds + K1_SCV))[row];
        unsigned int pk[4];
        pk[0] = f2bf(a[0] * sc) | (f2bf(a[1] * sc) << 16);
        pk[1] = f2bf(a[2] * sc) | (f2bf(a[3] * sc) << 16);
        pk[2] = f2bf(c[0] * sc) | (f2bf(c[1] * sc) << 16);
        pk[3] = f2bf(c[2] * sc) | (f2bf(c[3] * sc) << 16);
        u32x4 v = {pk[0], pk[1], pk[2], pk[3]};
        *(u32x4*)(lds + (row << 9) + ((col8 << 4) ^ ((row & 7) << 4))) = v;
    }

    int sdst_off = spx * 64 + ((scg << 4) ^ ((spx & 3) << 4));
    // write x step0
    {
        unsigned int pk[4];
#pragma unroll
        for (int j = 0; j < 4; j++)
            pk[j] = f2bf(xr[0][2 * j]) | (f2bf(xr[0][2 * j + 1]) << 16);
        u32x4 v = {pk[0], pk[1], pk[2], pk[3]};
        *(u32x4*)(lds + K1_XB0 + sdst_off) = v;
    }

    f32x4 acc[4];
#pragma unroll
    for (int n = 0; n < 4; n++) acc[n] = (f32x4){0.f, 0.f, 0.f, 0.f};
    int arow = w * 16 + (lane & 15);
    int a_off = arow * 64 + (((lane >> 4) << 4) ^ ((arow & 3) << 4));

#pragma unroll
    for (int ks = 0; ks < 8; ks++) {
        __syncthreads();       // 1 barrier/step: write(k+1) ∥ mfma(k), dbuf
        if (ks < 7) {
            unsigned int pk[4];
#pragma unroll
            for (int j = 0; j < 4; j++)
                pk[j] = f2bf(xr[ks + 1][2 * j]) | (f2bf(xr[ks + 1][2 * j + 1]) << 16);
            u32x4 v = {pk[0], pk[1], pk[2], pk[3]};
            *(u32x4*)(lds + (((ks + 1) & 1) ? K1_XB1 : K1_XB0) + sdst_off) = v;
        }
        short8 a = *(const short8*)(lds + ((ks & 1) ? K1_XB1 : K1_XB0) + a_off);
#pragma unroll
        for (int n = 0; n < 4; n++) {
            int brow = n * 16 + (lane & 15);
            short8 bb = *(const short8*)(lds + (brow << 9) +
                          ((ks * 64 + ((lane >> 4) << 4)) ^ ((brow & 7) << 4)));
            acc[n] = __builtin_amdgcn_mfma_f32_16x16x32_bf16(a, bb, acc[n], 0, 0, 0);
        }
    }

    // epilogue: h_g[(b*HW+px)*64 + o] = relu(acc + bias)
#pragma unroll
    for (int n = 0; n < 4; n++) {
        int o = n * 16 + (lane & 15);
        float bo = ((const float*)(lds + K1_BIAS))[o];
#pragma unroll
        for (int r = 0; r < 4; r++) {
            int pxl = w * 16 + ((lane >> 4) << 2) + r;
            if (pxl < 56) {
                float v = fmaxf(acc[n][r] + bo, 0.f);
                h_g[((size_t)b * HW + px0 + pxl) * 64 + o] = (ushort_t)f2bf(v);
            }
        }
    }
}

// k2: fused weight-GEMM (bf16 MFMA) + involution.
// 4-row tile (224 px), 896 blocks, 256 threads, XCD-chunked decode.
__global__ __launch_bounds__(256, 4) void k2_fused(
        const float* __restrict__ x, const ushort_t* __restrict__ h_g,
        const float* __restrict__ w2, const float* __restrict__ b2,
        float* __restrict__ out) {
    __shared__ __align__(16) char lds[K2_TOT];
    // bijective XCD decode: 896 = 8 xcd * 112; per-XCD span = half-batch, 7 tiles, all g
    int wid0 = blockIdx.x;
    int xcd = wid0 & 7, pos = wid0 >> 3;
    int work = xcd * 112 + pos;
    int b = work / 224;
    int rem = work - b * 224;
    int half = rem / 112, r2 = rem - half * 112;
    int tloc = r2 >> 4, g = r2 & 15;
    int tile = half * 7 + tloc;                    // 0..13, rows [tile*4, tile*4+4)
    int tid = threadIdx.x;

    // ---- Phase A1: stage h tile (224 px rows x 64c bf16), XOR-swizzled ----
    const char* hg = (const char*)h_g + ((size_t)b * HW + tile * 224) * 128;
    for (int i = tid; i < 1792; i += 256) {        // 16B chunks
        int row = i >> 3, cb = (i & 7) << 4;
        u32x4 v = *(const u32x4*)(hg + row * 128 + cb);
        *(u32x4*)(lds + row * 128 + (cb ^ ((row & 7) << 4))) = v;
    }
    // ---- Phase A2: w2 group -> bf16, rows padded to 64 taps, swizzled ----
    {
        int k = tid >> 2, cg = tid & 3;
        unsigned int pk[8];
        if (k < 49) {
            const float* wr = w2 + ((size_t)(g * 49 + k)) * 64 + cg * 16;
#pragma unroll
            for (int i = 0; i < 8; i++)
                pk[i] = f2bf(wr[2 * i]) | (f2bf(wr[2 * i + 1]) << 16);
        } else {
#pragma unroll
            for (int i = 0; i < 8; i++) pk[i] = 0;
        }
#pragma unroll
        for (int hh = 0; hh < 2; hh++) {
            u32x4 v = {pk[hh * 4 + 0], pk[hh * 4 + 1], pk[hh * 4 + 2], pk[hh * 4 + 3]};
            *(u32x4*)(lds + K2_W2P + k * 128 + ((cg * 32 + hh * 16) ^ ((k & 7) << 4))) = v;
        }
    }
    if (tid < 49) ((float*)(lds + K2_B2S))[tid] = b2[g * 49 + tid];
    __syncthreads();

    // ---- Phase B: wgt[64tap][224px] = w2p(64x64) @ h(64c x 224px) via MFMA ----
    int lane = tid & 63, wd = tid >> 6;
    f32x4 acc[14];
#pragma unroll
    for (int n = 0; n < 14; n++) acc[n] = (f32x4){0.f, 0.f, 0.f, 0.f};
    int arow = wd * 16 + (lane & 15);
#pragma unroll
    for (int ks = 0; ks < 2; ks++) {
        int kc = ks * 64 + ((lane >> 4) << 4);       // byte col of 8 bf16 k-chunk
        short8 a = *(const short8*)(lds + K2_W2P + arow * 128 + (kc ^ ((arow & 7) << 4)));
#pragma unroll
        for (int n = 0; n < 14; n++) {
            int brow = n * 16 + (lane & 15);
            short8 bb = *(const short8*)(lds + brow * 128 + (kc ^ ((brow & 7) << 4)));
            acc[n] = __builtin_amdgcn_mfma_f32_16x16x32_bf16(a, bb, acc[n], 0, 0, 0);
        }
    }
    __syncthreads();    // all B-reads done before overwriting h_t/w2p with wgt

    // ---- Epilogue: wgt bf16 [64][232] @0 (aliases h/w2p), +bias ----
    {
        const float* b2s = (const float*)(lds + K2_B2S);
        ushort_t* wl = (ushort_t*)lds;
#pragma unroll
        for (int n = 0; n < 14; n++) {
#pragma unroll
            for (int rr = 0; rr < 4; rr++) {
                int tap = wd * 16 + ((lane >> 4) << 2) + rr;
                if (tap < 49) {
                    int px = n * 16 + (lane & 15);
                    wl[tap * 232 + px] = (ushort_t)f2bf(acc[n][rr] + b2s[tap]);
                }
            }
        }
    }
    __syncthreads();

    // ---- Phase D: involution. thread = (2 channels, 8 contiguous px) ----
    int cpk = tid >> 5;            // 0..7 channel-pair
    int pg = tid & 31;
    int py = pg >> 3, xi = pg & 7; // 4 rows x 7 octets (xi<7 active)
    if (xi < 7) {
        int x0 = xi * 8;
        int c0 = g * 16 + cpk * 2;
        int rowb = tile * 4 + py;
        int base0 = (b * 256 + c0) * HW;
        bool edge = (tile == 0) || (tile == 13);   // block-uniform -> scalar branch
        float accd[2][8];
#pragma unroll
        for (int cc = 0; cc < 2; cc++)
#pragma unroll
            for (int pi = 0; pi < 8; pi++) accd[cc][pi] = 0.f;

#pragma unroll
        for (int ky = 0; ky < 7; ky++) {
            int rr = rowb + ky - 3;
            int rrc = min(max(rr, 0), 55);
            float rowok = (rr >= 0 && rr < 56) ? 1.f : 0.f;
            float w[2][16];
#pragma unroll
            for (int cc = 0; cc < 2; cc++) {
                int base = base0 + cc * HW + rrc * 56 + x0 - 4;
#pragma unroll
                for (int k4 = 0; k4 < 4; k4++) {
                    int o = base + k4 * 4;
                    if (k4 == 0) o = max(o, 0);        // only row0/col0 corner
                    if (k4 == 3) o = min(o, NX - 4);   // only last-channel tail
                    *(f32x4*)&w[cc][k4 * 4] = *(const f32x4*)(x + o);
                }
            }
            if (edge) {                                // zero padded rows
#pragma unroll
                for (int cc = 0; cc < 2; cc++)
#pragma unroll
                    for (int j = 0; j < 16; j++) w[cc][j] *= rowok;
            }
            if (x0 == 0) {                             // img cols < 0
#pragma unroll
                for (int cc = 0; cc < 2; cc++) { w[cc][1] = w[cc][2] = w[cc][3] = 0.f; }
            }
            if (x0 == 48) {                            // img cols > 55
#pragma unroll
                for (int cc = 0; cc < 2; cc++) { w[cc][12] = w[cc][13] = w[cc][14] = 0.f; }
            }
#pragma unroll
            for (int kx = 0; kx < 7; kx++) {
                // 8 bf16 weights for px x0..x0+7 of tap (ky,kx)
                u32x4 wv = *(const u32x4*)(lds + ((ky * 7 + kx) * 232 + py * 56 + x0) * 2);
                float wf[8];
#pragma unroll
                for (int j = 0; j < 4; j++) {
                    wf[2 * j]     = __uint_as_float(wv[j] << 16);
                    wf[2 * j + 1] = __uint_as_float(wv[j] & 0xFFFF0000u);
                }
#pragma unroll
                for (int cc = 0; cc < 2; cc++)
#pragma unroll
                    for (int pi = 0; pi < 8; pi++)
                        accd[cc][pi] = fmaf(wf[pi], w[cc][pi + kx + 1], accd[cc][pi]);
            }
        }
#pragma unroll
        for (int cc = 0; cc < 2; cc++) {
            float* op = out + (size_t)(b * 256 + c0 + cc) * HW + tile * 224 + py * 56 + x0;
            *(f32x4*)op = (f32x4){accd[cc][0], accd[cc][1], accd[cc][2], accd[cc][3]};
            *(f32x4*)(op + 4) = (f32x4){accd[cc][4], accd[cc][5], accd[cc][6], accd[cc][7]};
        }
    }
}

extern "C" void kernel_launch(void* const* d_in, const int* in_sizes, int n_in,
                              void* d_out, int out_size, void* d_ws, size_t ws_size,
                              hipStream_t stream) {
    const float* x     = (const float*)d_in[0];
    const float* w1    = (const float*)d_in[1];
    const float* gamma = (const float*)d_in[2];
    const float* beta  = (const float*)d_in[3];
    const float* mean  = (const float*)d_in[4];
    const float* var   = (const float*)d_in[5];
    const float* w2    = (const float*)d_in[6];
    const float* b2    = (const float*)d_in[7];
    float* out = (float*)d_out;

    ushort_t* h_g = (ushort_t*)d_ws;               // [B][3136][64] bf16 = 1.6 MB

    k1_mfma<<<224, 256, 0, stream>>>(x, w1, gamma, beta, mean, var, h_g);
    k2_fused<<<896, 256, 0, stream>>>(x, h_g, w2, b2, out);
}

// Round 7
// 32.382 us; speedup vs baseline: 15.2269x; 15.2269x over previous
//
#include <hip/hip_runtime.h>

typedef __attribute__((ext_vector_type(8))) short short8;
typedef __attribute__((ext_vector_type(4))) float f32x4;
typedef __attribute__((ext_vector_type(4))) unsigned int u32x4;
typedef unsigned short ushort_t;

#define BB 4
#define HW 3136
#define NX (4*256*3136)          // total x elements

// k1 LDS regions: w1 [64][512B] @0, x dbuf @32768/@36864, bias/scv
#define K1_XB0 32768
#define K1_XB1 36864
#define K1_BIAS 40960
#define K1_SCV 41216
#define K1_TOT 41472

// k2 LDS regions (4-row tile): h 224*128 @0, w2p @28672, bias @36864
// wgt bf16 [64][232] @0 (aliases h+w2p after phase B)
#define K2_W2P 28672
#define K2_B2S 36864
#define K2_TOT 37120

__device__ __forceinline__ unsigned int f2bf(float f) {
    unsigned int u = __float_as_uint(f);
    return (u + 0x7FFFu + ((u >> 16) & 1u)) >> 16;   // RNE to bf16 bits
}

// k1: h = relu(conv1+bn) via bf16 MFMA, BN fold fused into w1 staging.
// All 64 x values per thread loaded UPFRONT (full-K register prefetch) so the
// 8 K-steps never wait on HBM. h_g[b][px][64c] bf16. Block = 56-px tile, 4 waves.
__global__ __launch_bounds__(256) void k1_mfma(
        const float* __restrict__ x, const float* __restrict__ w1,
        const float* __restrict__ gamma, const float* __restrict__ beta,
        const float* __restrict__ mean, const float* __restrict__ var,
        ushort_t* __restrict__ h_g) {
    __shared__ __align__(16) char lds[K1_TOT];
    int blk = blockIdx.x;
    int tile = blk % 56, b = blk / 56;
    int px0 = tile * 56;
    int tid = threadIdx.x;
    int lane = tid & 63, w = tid >> 6;

    // BN params FIRST (oldest in vmem queue -> consuming them doesn't drain x loads)
    float gs = 0.f, bs = 0.f, ms = 0.f, vs = 0.f;
    if (tid < 64) { gs = gamma[tid]; bs = beta[tid]; ms = mean[tid]; vs = var[tid]; }

    // issue ALL x loads upfront: thread -> (px = tid&63, cg = tid>>6), 8 c x 8 steps
    int spx = tid & 63, scg = tid >> 6;
    int gpx = min(px0 + spx, HW - 1);              // clamp pad px (masked at epilogue)
    const float* xbase = x + (size_t)b * 256 * HW + gpx;
    float xr[8][8];
#pragma unroll
    for (int s = 0; s < 8; s++)
#pragma unroll
        for (int u = 0; u < 8; u++)
            xr[s][u] = xbase[(size_t)(s * 32 + scg * 8 + u) * HW];

    if (tid < 64) {
        float sc = gs * rsqrtf(vs + 1e-5f);
        ((float*)(lds + K1_SCV))[tid] = sc;
        ((float*)(lds + K1_BIAS))[tid] = bs - ms * sc;
    }
    __syncthreads();

    // stage w1 [64o][256c] -> bf16*scale, rows 512B, XOR-swizzled
#pragma unroll
    for (int ii = 0; ii < 8; ii++) {
        int i = tid + ii * 256;
        int row = i >> 5, col8 = i & 31;
        const float* src = w1 + row * 256 + col8 * 8;
        f32x4 a = *(const f32x4*)src;
        f32x4 c = *(const f32x4*)(src + 4);
        float sc = ((const float*)(lds + K1_SCV))[row];
        unsigned int pk[4];
        pk[0] = f2bf(a[0] * sc) | (f2bf(a[1] * sc) << 16);
        pk[1] = f2bf(a[2] * sc) | (f2bf(a[3] * sc) << 16);
        pk[2] = f2bf(c[0] * sc) | (f2bf(c[1] * sc) << 16);
        pk[3] = f2bf(c[2] * sc) | (f2bf(c[3] * sc) << 16);
        u32x4 v = {pk[0], pk[1], pk[2], pk[3]};
        *(u32x4*)(lds + (row << 9) + ((col8 << 4) ^ ((row & 7) << 4))) = v;
    }

    int sdst_off = spx * 64 + ((scg << 4) ^ ((spx & 3) << 4));
    // write x step0
    {
        unsigned int pk[4];
#pragma unroll
        for (int j = 0; j < 4; j++)
            pk[j] = f2bf(xr[0][2 * j]) | (f2bf(xr[0][2 * j + 1]) << 16);
        u32x4 v = {pk[0], pk[1], pk[2], pk[3]};
        *(u32x4*)(lds + K1_XB0 + sdst_off) = v;
    }

    f32x4 acc[4];
#pragma unroll
    for (int n = 0; n < 4; n++) acc[n] = (f32x4){0.f, 0.f, 0.f, 0.f};
    int arow = w * 16 + (lane & 15);
    int a_off = arow * 64 + (((lane >> 4) << 4) ^ ((arow & 3) << 4));

#pragma unroll
    for (int ks = 0; ks < 8; ks++) {
        __syncthreads();       // 1 barrier/step: write(k+1) ∥ mfma(k), dbuf
        if (ks < 7) {
            unsigned int pk[4];
#pragma unroll
            for (int j = 0; j < 4; j++)
                pk[j] = f2bf(xr[ks + 1][2 * j]) | (f2bf(xr[ks + 1][2 * j + 1]) << 16);
            u32x4 v = {pk[0], pk[1], pk[2], pk[3]};
            *(u32x4*)(lds + (((ks + 1) & 1) ? K1_XB1 : K1_XB0) + sdst_off) = v;
        }
        short8 a = *(const short8*)(lds + ((ks & 1) ? K1_XB1 : K1_XB0) + a_off);
#pragma unroll
        for (int n = 0; n < 4; n++) {
            int brow = n * 16 + (lane & 15);
            short8 bb = *(const short8*)(lds + (brow << 9) +
                          ((ks * 64 + ((lane >> 4) << 4)) ^ ((brow & 7) << 4)));
            acc[n] = __builtin_amdgcn_mfma_f32_16x16x32_bf16(a, bb, acc[n], 0, 0, 0);
        }
    }

    // epilogue: h_g[(b*HW+px)*64 + o] = relu(acc + bias)
#pragma unroll
    for (int n = 0; n < 4; n++) {
        int o = n * 16 + (lane & 15);
        float bo = ((const float*)(lds + K1_BIAS))[o];
#pragma unroll
        for (int r = 0; r < 4; r++) {
            int pxl = w * 16 + ((lane >> 4) << 2) + r;
            if (pxl < 56) {
                float v = fmaxf(acc[n][r] + bo, 0.f);
                h_g[((size_t)b * HW + px0 + pxl) * 64 + o] = (ushort_t)f2bf(v);
            }
        }
    }
}

// k2: fused weight-GEMM (bf16 MFMA) + involution.
// 4-row tile (224 px), 896 blocks, 256 threads, XCD-chunked decode.
// Phase D uses the round-5 dynamic ky loop: the `continue` keeps the live
// range of the x loads to ONE ky iteration (full unroll spilled to scratch).
__global__ __launch_bounds__(256, 4) void k2_fused(
        const float* __restrict__ x, const ushort_t* __restrict__ h_g,
        const float* __restrict__ w2, const float* __restrict__ b2,
        float* __restrict__ out) {
    __shared__ __align__(16) char lds[K2_TOT];
    // bijective XCD decode: 896 = 8 xcd * 112; per-XCD span = half-batch, 7 tiles, all g
    int wid0 = blockIdx.x;
    int xcd = wid0 & 7, pos = wid0 >> 3;
    int work = xcd * 112 + pos;
    int b = work / 224;
    int rem = work - b * 224;
    int half = rem / 112, r2 = rem - half * 112;
    int tloc = r2 >> 4, g = r2 & 15;
    int tile = half * 7 + tloc;                    // 0..13, rows [tile*4, tile*4+4)
    int tid = threadIdx.x;

    // ---- Phase A1: stage h tile (224 px rows x 64c bf16), XOR-swizzled ----
    const char* hg = (const char*)h_g + ((size_t)b * HW + tile * 224) * 128;
    for (int i = tid; i < 1792; i += 256) {        // 16B chunks
        int row = i >> 3, cb = (i & 7) << 4;
        u32x4 v = *(const u32x4*)(hg + row * 128 + cb);
        *(u32x4*)(lds + row * 128 + (cb ^ ((row & 7) << 4))) = v;
    }
    // ---- Phase A2: w2 group -> bf16, rows padded to 64 taps, swizzled ----
    {
        int k = tid >> 2, cg = tid & 3;
        unsigned int pk[8];
        if (k < 49) {
            const float* wr = w2 + ((size_t)(g * 49 + k)) * 64 + cg * 16;
#pragma unroll
            for (int i = 0; i < 8; i++)
                pk[i] = f2bf(wr[2 * i]) | (f2bf(wr[2 * i + 1]) << 16);
        } else {
#pragma unroll
            for (int i = 0; i < 8; i++) pk[i] = 0;
        }
#pragma unroll
        for (int hh = 0; hh < 2; hh++) {
            u32x4 v = {pk[hh * 4 + 0], pk[hh * 4 + 1], pk[hh * 4 + 2], pk[hh * 4 + 3]};
            *(u32x4*)(lds + K2_W2P + k * 128 + ((cg * 32 + hh * 16) ^ ((k & 7) << 4))) = v;
        }
    }
    if (tid < 49) ((float*)(lds + K2_B2S))[tid] = b2[g * 49 + tid];
    __syncthreads();

    // ---- Phase B: wgt[64tap][224px] = w2p(64x64) @ h(64c x 224px) via MFMA ----
    int lane = tid & 63, wd = tid >> 6;
    f32x4 acc[14];
#pragma unroll
    for (int n = 0; n < 14; n++) acc[n] = (f32x4){0.f, 0.f, 0.f, 0.f};
    int arow = wd * 16 + (lane & 15);
#pragma unroll
    for (int ks = 0; ks < 2; ks++) {
        int kc = ks * 64 + ((lane >> 4) << 4);       // byte col of 8 bf16 k-chunk
        short8 a = *(const short8*)(lds + K2_W2P + arow * 128 + (kc ^ ((arow & 7) << 4)));
#pragma unroll
        for (int n = 0; n < 14; n++) {
            int brow = n * 16 + (lane & 15);
            short8 bb = *(const short8*)(lds + brow * 128 + (kc ^ ((brow & 7) << 4)));
            acc[n] = __builtin_amdgcn_mfma_f32_16x16x32_bf16(a, bb, acc[n], 0, 0, 0);
        }
    }
    __syncthreads();    // all B-reads done before overwriting h_t/w2p with wgt

    // ---- Epilogue: wgt bf16 [64][232] @0 (aliases h/w2p), +bias ----
    {
        const float* b2s = (const float*)(lds + K2_B2S);
        ushort_t* wl = (ushort_t*)lds;
#pragma unroll
        for (int n = 0; n < 14; n++) {
#pragma unroll
            for (int rr = 0; rr < 4; rr++) {
                int tap = wd * 16 + ((lane >> 4) << 2) + rr;
                if (tap < 49) {
                    int px = n * 16 + (lane & 15);
                    wl[tap * 232 + px] = (ushort_t)f2bf(acc[n][rr] + b2s[tap]);
                }
            }
        }
    }
    __syncthreads();

    // ---- Phase D: involution. thread = (2 channels, 8 contiguous px) ----
    int cpk = tid >> 5;            // 0..7 channel-pair
    int pg = tid & 31;
    int py = pg >> 3, xi = pg & 7; // 4 rows x 7 octets (xi<7 active)
    if (xi < 7) {
        int x0 = xi * 8;
        int c0 = g * 16 + cpk * 2;
        int rowb = tile * 4 + py;
        float accd[2][8];
#pragma unroll
        for (int cc = 0; cc < 2; cc++)
#pragma unroll
            for (int pi = 0; pi < 8; pi++) accd[cc][pi] = 0.f;

        for (int ky = 0; ky < 7; ky++) {
            int rr = rowb + ky - 3;
            if (rr < 0 || rr >= 56) continue;      // zero-pad rows contribute 0
            float w[2][16];
#pragma unroll
            for (int cc = 0; cc < 2; cc++) {
                int base = (b * 256 + c0 + cc) * HW + rr * 56 + x0 - 4;
#pragma unroll
                for (int k4 = 0; k4 < 4; k4++) {
                    int o = base + k4 * 4;
                    o = min(max(o, 0), NX - 4);    // clamp; OOB values zeroed below
                    *(f32x4*)&w[cc][k4 * 4] = *(const f32x4*)(x + o);
                }
            }
            if (x0 == 0) {                          // img cols < 0
#pragma unroll
                for (int cc = 0; cc < 2; cc++) { w[cc][1] = w[cc][2] = w[cc][3] = 0.f; }
            }
            if (x0 == 48) {                         // img cols > 55
#pragma unroll
                for (int cc = 0; cc < 2; cc++) { w[cc][12] = w[cc][13] = w[cc][14] = 0.f; }
            }
#pragma unroll
            for (int kx = 0; kx < 7; kx++) {
                // 8 bf16 weights for px x0..x0+7 of tap (ky,kx)
                u32x4 wv = *(const u32x4*)(lds + ((ky * 7 + kx) * 232 + py * 56 + x0) * 2);
                float wf[8];
#pragma unroll
                for (int j = 0; j < 4; j++) {
                    wf[2 * j]     = __uint_as_float(wv[j] << 16);
                    wf[2 * j + 1] = __uint_as_float(wv[j] & 0xFFFF0000u);
                }
#pragma unroll
                for (int cc = 0; cc < 2; cc++)
#pragma unroll
                    for (int pi = 0; pi < 8; pi++)
                        accd[cc][pi] = fmaf(wf[pi], w[cc][pi + kx + 1], accd[cc][pi]);
            }
        }
#pragma unroll
        for (int cc = 0; cc < 2; cc++) {
            float* op = out + (size_t)(b * 256 + c0 + cc) * HW + tile * 224 + py * 56 + x0;
            *(f32x4*)op = (f32x4){accd[cc][0], accd[cc][1], accd[cc][2], accd[cc][3]};
            *(f32x4*)(op + 4) = (f32x4){accd[cc][4], accd[cc][5], accd[cc][6], accd[cc][7]};
        }
    }
}

extern "C" void kernel_launch(void* const* d_in, const int* in_sizes, int n_in,
                              void* d_out, int out_size, void* d_ws, size_t ws_size,
                              hipStream_t stream) {
    const float* x     = (const float*)d_in[0];
    const float* w1    = (const float*)d_in[1];
    const float* gamma = (const float*)d_in[2];
    const float* beta  = (const float*)d_in[3];
    const float* mean  = (const float*)d_in[4];
    const float* var   = (const float*)d_in[5];
    const float* w2    = (const float*)d_in[6];
    const float* b2    = (const float*)d_in[7];
    float* out = (float*)d_out;

    ushort_t* h_g = (ushort_t*)d_ws;               // [B][3136][64] bf16 = 1.6 MB

    k1_mfma<<<224, 256, 0, stream>>>(x, w1, gamma, beta, mean, var, h_g);
    k2_fused<<<896, 256, 0, stream>>>(x, h_g, w2, b2, out);
}